// Round 1
// baseline (389.693 us; speedup 1.0000x reference)
//
#include <hip/hip_runtime.h>
#include <hip/hip_bf16.h>
#include <stdint.h>

#define DIM   1024
#define HEADS 16
#define HD    64
#define NB    8
#define NTOK  1024
#define MROWS (NB*NTOK)   // 8192 rows for x and for context

typedef __attribute__((ext_vector_type(8))) _Float16 f16x8;
typedef __attribute__((ext_vector_type(4))) _Float16 f16x4;
typedef __attribute__((ext_vector_type(4))) float    f32x4;

typedef unsigned int uint_as1 __attribute__((address_space(1)));
typedef unsigned int uint_as3 __attribute__((address_space(3)));

__device__ __forceinline__ void gload16(const void* g, void* l) {
    __builtin_amdgcn_global_load_lds((const uint_as1*)g, (uint_as3*)l, 16, 0, 0);
}

// ---------------- LayerNorm: fp32 in -> fp16 out ----------------
__global__ __launch_bounds__(256) void ln_kernel(const float* __restrict__ x,
                                                 const float* __restrict__ ctx,
                                                 const float* __restrict__ gamma,
                                                 const float* __restrict__ beta,
                                                 _Float16* __restrict__ xn,
                                                 _Float16* __restrict__ cn) {
    int row = blockIdx.x;
    const float* src; _Float16* dst;
    if (row < MROWS) { src = x + (size_t)row * DIM;          dst = xn + (size_t)row * DIM; }
    else             { int r = row - MROWS;
                       src = ctx + (size_t)r * DIM;          dst = cn + (size_t)r * DIM; }
    int t = threadIdx.x;
    float4 v = *(const float4*)(src + t * 4);
    float s  = v.x + v.y + v.z + v.w;
    float s2 = v.x*v.x + v.y*v.y + v.z*v.z + v.w*v.w;
    #pragma unroll
    for (int o = 32; o; o >>= 1) { s += __shfl_xor(s, o, 64); s2 += __shfl_xor(s2, o, 64); }
    __shared__ float red[8];
    int w = t >> 6, l = t & 63;
    if (l == 0) { red[w] = s; red[4 + w] = s2; }
    __syncthreads();
    s  = red[0] + red[1] + red[2] + red[3];
    s2 = red[4] + red[5] + red[6] + red[7];
    float mu   = s * (1.0f / DIM);
    float rstd = rsqrtf(s2 * (1.0f / DIM) - mu * mu + 1e-5f);
    float4 g  = *(const float4*)(gamma + t * 4);
    float4 bb = *(const float4*)(beta  + t * 4);
    f16x4 o;
    o[0] = (_Float16)((v.x - mu) * rstd * g.x + bb.x);
    o[1] = (_Float16)((v.y - mu) * rstd * g.y + bb.y);
    o[2] = (_Float16)((v.z - mu) * rstd * g.z + bb.z);
    o[3] = (_Float16)((v.w - mu) * rstd * g.w + bb.w);
    *(f16x4*)(dst + t * 4) = o;
}

// ---------------- Weight transpose + cast: W[k][j] fp32 -> WT[j][k] fp16 ----
__global__ __launch_bounds__(256) void wtrans_kernel(const float* __restrict__ Wq, const float* __restrict__ Wk,
                                                     const float* __restrict__ Wv, const float* __restrict__ Wo,
                                                     _Float16* __restrict__ Tq, _Float16* __restrict__ Tk,
                                                     _Float16* __restrict__ Tv, _Float16* __restrict__ To) {
    __shared__ float tile[32][33];
    int m = blockIdx.z;
    const float* W = (m == 0) ? Wq : (m == 1) ? Wk : (m == 2) ? Wv : Wo;
    _Float16*    T = (m == 0) ? Tq : (m == 1) ? Tk : (m == 2) ? Tv : To;
    int j0 = blockIdx.x * 32, k0 = blockIdx.y * 32;
    int tx = threadIdx.x, ty = threadIdx.y;   // 32 x 8
    #pragma unroll
    for (int i = 0; i < 4; i++) tile[ty + i*8][tx] = W[(size_t)(k0 + ty + i*8) * DIM + j0 + tx];
    __syncthreads();
    #pragma unroll
    for (int i = 0; i < 4; i++) T[(size_t)(j0 + ty + i*8) * DIM + k0 + tx] = (_Float16)tile[tx][ty + i*8];
}

// ---------------- GEMM: C = A @ BT^T, A[M][1024] f16, BT[1024][1024] f16 ----
// MODE 0: C -> [b][h][n][d] f16 (Q/K layout)
// MODE 2: C -> [b][h][d][n] f16 (V transposed layout)
// MODE 3: C -> fp32 [m][j] + bias[j]
template<int MODE>
__global__ __launch_bounds__(256) void gemm_bt(const _Float16* __restrict__ A,
                                               const _Float16* __restrict__ BT,
                                               void* __restrict__ Cout,
                                               const float* __restrict__ bias) {
    __shared__ _Float16 As[128 * 32];
    __shared__ _Float16 Bs[128 * 32];
    const int K = DIM;
    int m0 = blockIdx.x * 128, n0 = blockIdx.y * 128;
    int t = threadIdx.x, w = t >> 6, l = t & 63;
    int wr = w >> 1, wc = w & 1, ln = l & 15, qtr = l >> 4;
    f32x4 acc[4][4] = {};
    int srow = t >> 2, scol = (t & 3) * 8;
    const _Float16* Ag = A  + (size_t)(m0 + srow) * K + scol;
    const _Float16* Bg = BT + (size_t)(n0 + srow) * K + scol;
    _Float16* Al = &As[(w * 16) * 32];   // wave-uniform LDS base
    _Float16* Bl = &Bs[(w * 16) * 32];
    for (int kt = 0; kt < K; kt += 32) {
        gload16(Ag,                    Al);
        gload16(Ag + (size_t)64 * K,   Al + 64 * 32);
        gload16(Bg,                    Bl);
        gload16(Bg + (size_t)64 * K,   Bl + 64 * 32);
        Ag += 32; Bg += 32;
        __syncthreads();
        f16x8 af[4], bfr[4];
        #pragma unroll
        for (int r = 0; r < 4; r++) af[r]  = *(const f16x8*)&As[(wr * 64 + r * 16 + ln) * 32 + qtr * 8];
        #pragma unroll
        for (int c = 0; c < 4; c++) bfr[c] = *(const f16x8*)&Bs[(wc * 64 + c * 16 + ln) * 32 + qtr * 8];
        #pragma unroll
        for (int r = 0; r < 4; r++)
            #pragma unroll
            for (int c = 0; c < 4; c++)
                acc[r][c] = __builtin_amdgcn_mfma_f32_16x16x32_f16(af[r], bfr[c], acc[r][c], 0, 0, 0);
        __syncthreads();
    }
    #pragma unroll
    for (int r = 0; r < 4; r++)
        #pragma unroll
        for (int c = 0; c < 4; c++) {
            int gn = n0 + wc * 64 + c * 16 + ln;
            #pragma unroll
            for (int q = 0; q < 4; q++) {
                int gm = m0 + wr * 64 + r * 16 + qtr * 4 + q;
                float v = acc[r][c][q];
                if constexpr (MODE == 0) {
                    int b = gm >> 10, n = gm & 1023, h = gn >> 6, d = gn & 63;
                    ((_Float16*)Cout)[(((size_t)(b * HEADS + h) * NTOK + n) << 6) + d] = (_Float16)v;
                } else if constexpr (MODE == 2) {
                    int b = gm >> 10, n = gm & 1023, h = gn >> 6, d = gn & 63;
                    ((_Float16*)Cout)[(((size_t)(b * HEADS + h) * HD + d) << 10) + n] = (_Float16)v;
                } else {
                    ((float*)Cout)[(size_t)gm * DIM + gn] = v + bias[gn];
                }
            }
        }
}

// ---------------- Fused attention: per (b, h, 16 q-rows) -------------------
// scores in registers, softmax across block, P via LDS, PV from VT (global)
__global__ __launch_bounds__(256) void attn_kernel(const _Float16* __restrict__ qb,
                                                   const _Float16* __restrict__ kb,
                                                   const _Float16* __restrict__ vt,
                                                   const float* __restrict__ bias,
                                                   _Float16* __restrict__ ao) {
    __shared__ _Float16 P[16][1032];   // padded row stride (16B-aligned)
    __shared__ float redm[4][16];
    __shared__ float reds[4][16];
    int bid = blockIdx.x;
    int qt = bid & 63, h = (bid >> 6) & 15, b = bid >> 10;
    int q0 = qt * 16;
    int t = threadIdx.x, w = t >> 6, l = t & 63, ln = l & 15, qtr = l >> 4;
    const _Float16* qbase = qb + (size_t)(b * HEADS + h) * NTOK * HD;
    const _Float16* kbase = kb + (size_t)(b * HEADS + h) * NTOK * HD;
    const _Float16* vbase = vt + (size_t)(b * HEADS + h) * HD * NTOK;

    f16x8 qa0 = *(const f16x8*)&qbase[(q0 + ln) * HD + qtr * 8];
    f16x8 qa1 = *(const f16x8*)&qbase[(q0 + ln) * HD + 32 + qtr * 8];

    // QK^T: wave w covers keys [w*256, w*256+256)
    f32x4 s[16];
    #pragma unroll
    for (int c = 0; c < 16; c++) {
        int j = w * 256 + c * 16;
        f16x8 kf0 = *(const f16x8*)&kbase[(j + ln) * HD + qtr * 8];
        f16x8 kf1 = *(const f16x8*)&kbase[(j + ln) * HD + 32 + qtr * 8];
        f32x4 acc = {0.f, 0.f, 0.f, 0.f};
        acc = __builtin_amdgcn_mfma_f32_16x16x32_f16(qa0, kf0, acc, 0, 0, 0);
        acc = __builtin_amdgcn_mfma_f32_16x16x32_f16(qa1, kf1, acc, 0, 0, 0);
        s[c] = acc;
    }
    // scale + bias, per-lane row max (lane holds rows qtr*4+q, col w*256+c*16+ln)
    const float* brow = bias + ((size_t)h * NTOK + q0 + qtr * 4) * NTOK + w * 256 + ln;
    float mx[4] = {-3e38f, -3e38f, -3e38f, -3e38f};
    #pragma unroll
    for (int c = 0; c < 16; c++)
        #pragma unroll
        for (int q = 0; q < 4; q++) {
            float v = s[c][q] * 0.125f + brow[(size_t)q * NTOK + c * 16];
            s[c][q] = v;
            mx[q] = fmaxf(mx[q], v);
        }
    #pragma unroll
    for (int q = 0; q < 4; q++) {
        #pragma unroll
        for (int o = 8; o; o >>= 1) mx[q] = fmaxf(mx[q], __shfl_xor(mx[q], o, 64));
    }
    if (ln == 0) {
        #pragma unroll
        for (int q = 0; q < 4; q++) redm[w][qtr * 4 + q] = mx[q];
    }
    __syncthreads();
    float M[4], sm[4] = {0.f, 0.f, 0.f, 0.f};
    #pragma unroll
    for (int q = 0; q < 4; q++) {
        int row = qtr * 4 + q;
        M[q] = fmaxf(fmaxf(redm[0][row], redm[1][row]), fmaxf(redm[2][row], redm[3][row]));
    }
    #pragma unroll
    for (int c = 0; c < 16; c++)
        #pragma unroll
        for (int q = 0; q < 4; q++) {
            float p = __expf(s[c][q] - M[q]);
            s[c][q] = p;
            sm[q] += p;
        }
    #pragma unroll
    for (int q = 0; q < 4; q++) {
        #pragma unroll
        for (int o = 8; o; o >>= 1) sm[q] += __shfl_xor(sm[q], o, 64);
    }
    if (ln == 0) {
        #pragma unroll
        for (int q = 0; q < 4; q++) reds[w][qtr * 4 + q] = sm[q];
    }
    __syncthreads();
    float inv[4];
    #pragma unroll
    for (int q = 0; q < 4; q++) {
        int row = qtr * 4 + q;
        inv[q] = 1.f / (reds[0][row] + reds[1][row] + reds[2][row] + reds[3][row]);
    }
    #pragma unroll
    for (int c = 0; c < 16; c++)
        #pragma unroll
        for (int q = 0; q < 4; q++)
            P[qtr * 4 + q][w * 256 + c * 16 + ln] = (_Float16)(s[c][q] * inv[q]);
    __syncthreads();

    // PV: wave w computes output cols d0..d0+15 over all 1024 keys
    int d0 = w * 16;
    f32x4 o = {0.f, 0.f, 0.f, 0.f};
    #pragma unroll
    for (int js = 0; js < 32; js++) {
        f16x8 pa = *(const f16x8*)&P[ln][js * 32 + qtr * 8];
        f16x8 vb = *(const f16x8*)&vbase[(d0 + ln) * NTOK + js * 32 + qtr * 8];
        o = __builtin_amdgcn_mfma_f32_16x16x32_f16(pa, vb, o, 0, 0, 0);
    }
    #pragma unroll
    for (int q = 0; q < 4; q++) {
        int row = qtr * 4 + q;
        ao[((size_t)(b * NTOK + q0 + row)) * DIM + h * HD + d0 + ln] = (_Float16)o[q];
    }
}

extern "C" void kernel_launch(void* const* d_in, const int* in_sizes, int n_in,
                              void* d_out, int out_size, void* d_ws, size_t ws_size,
                              hipStream_t stream) {
    const float* x     = (const float*)d_in[0];
    const float* ctx   = (const float*)d_in[1];
    const float* bias  = (const float*)d_in[2];
    const float* Wq    = (const float*)d_in[3];
    const float* Wk    = (const float*)d_in[4];
    const float* Wv    = (const float*)d_in[5];
    const float* Wo    = (const float*)d_in[6];
    const float* bo    = (const float*)d_in[7];
    const float* gamma = (const float*)d_in[8];
    const float* beta  = (const float*)d_in[9];
    float* out = (float*)d_out;

    _Float16* ws  = (_Float16*)d_ws;
    _Float16* xn  = ws;                                  // 8192*1024
    _Float16* cn  = xn  + (size_t)MROWS * DIM;           // 8192*1024
    _Float16* wqT = cn  + (size_t)MROWS * DIM;           // 1024*1024
    _Float16* wkT = wqT + (size_t)DIM * DIM;
    _Float16* wvT = wkT + (size_t)DIM * DIM;
    _Float16* woT = wvT + (size_t)DIM * DIM;
    _Float16* qbf = woT + (size_t)DIM * DIM;             // 8192*1024, [b][h][n][d]
    _Float16* kbf = qbf + (size_t)MROWS * DIM;           // [b][h][n][d]
    _Float16* vtb = kbf + (size_t)MROWS * DIM;           // [b][h][d][n]
    _Float16* aob = vtb + (size_t)MROWS * DIM;           // 8192*1024, [b][n][h*d]

    ln_kernel<<<dim3(2 * MROWS), dim3(256), 0, stream>>>(x, ctx, gamma, beta, xn, cn);
    wtrans_kernel<<<dim3(32, 32, 4), dim3(32, 8), 0, stream>>>(Wq, Wk, Wv, Wo, wqT, wkT, wvT, woT);
    gemm_bt<0><<<dim3(64, 8), dim3(256), 0, stream>>>(xn, wqT, qbf, nullptr);
    gemm_bt<0><<<dim3(64, 8), dim3(256), 0, stream>>>(cn, wkT, kbf, nullptr);
    gemm_bt<2><<<dim3(64, 8), dim3(256), 0, stream>>>(cn, wvT, vtb, nullptr);
    attn_kernel<<<dim3(NB * HEADS * 64), dim3(256), 0, stream>>>(qbf, kbf, vtb, bias, aob);
    gemm_bt<3><<<dim3(64, 8), dim3(256), 0, stream>>>(aob, woT, out, bo);
}

// Round 3
// 268.149 us; speedup vs baseline: 1.4533x; 1.4533x over previous
//
#include <hip/hip_runtime.h>
#include <hip/hip_bf16.h>
#include <stdint.h>

#define DIM   1024
#define HEADS 16
#define HD    64
#define NB    8
#define NTOK  1024
#define MROWS (NB*NTOK)   // 8192 rows for x and for context

typedef __attribute__((ext_vector_type(8))) _Float16 f16x8;
typedef __attribute__((ext_vector_type(4))) _Float16 f16x4;
typedef __attribute__((ext_vector_type(4))) float    f32x4;

typedef unsigned int uint_as1 __attribute__((address_space(1)));
typedef unsigned int uint_as3 __attribute__((address_space(3)));

__device__ __forceinline__ void gload16(const void* g, void* l) {
    __builtin_amdgcn_global_load_lds((const uint_as1*)g, (uint_as3*)l, 16, 0, 0);
}

__device__ __forceinline__ unsigned pkrtz(float a, float b) {
    auto h = __builtin_amdgcn_cvt_pkrtz(a, b);   // __fp16 ext_vector(2)
    return __builtin_bit_cast(unsigned, h);
}

// ---------------- LayerNorm: fp32 in -> fp16 out ----------------
__global__ __launch_bounds__(256) void ln_kernel(const float* __restrict__ x,
                                                 const float* __restrict__ ctx,
                                                 const float* __restrict__ gamma,
                                                 const float* __restrict__ beta,
                                                 _Float16* __restrict__ xn,
                                                 _Float16* __restrict__ cn) {
    int row = blockIdx.x;
    const float* src; _Float16* dst;
    if (row < MROWS) { src = x + (size_t)row * DIM;          dst = xn + (size_t)row * DIM; }
    else             { int r = row - MROWS;
                       src = ctx + (size_t)r * DIM;          dst = cn + (size_t)r * DIM; }
    int t = threadIdx.x;
    float4 v = *(const float4*)(src + t * 4);
    float s  = v.x + v.y + v.z + v.w;
    float s2 = v.x*v.x + v.y*v.y + v.z*v.z + v.w*v.w;
    #pragma unroll
    for (int o = 32; o; o >>= 1) { s += __shfl_xor(s, o, 64); s2 += __shfl_xor(s2, o, 64); }
    __shared__ float red[8];
    int w = t >> 6, l = t & 63;
    if (l == 0) { red[w] = s; red[4 + w] = s2; }
    __syncthreads();
    s  = red[0] + red[1] + red[2] + red[3];
    s2 = red[4] + red[5] + red[6] + red[7];
    float mu   = s * (1.0f / DIM);
    float rstd = rsqrtf(s2 * (1.0f / DIM) - mu * mu + 1e-5f);
    float4 g  = *(const float4*)(gamma + t * 4);
    float4 bb = *(const float4*)(beta  + t * 4);
    f16x4 o;
    o[0] = (_Float16)((v.x - mu) * rstd * g.x + bb.x);
    o[1] = (_Float16)((v.y - mu) * rstd * g.y + bb.y);
    o[2] = (_Float16)((v.z - mu) * rstd * g.z + bb.z);
    o[3] = (_Float16)((v.w - mu) * rstd * g.w + bb.w);
    *(f16x4*)(dst + t * 4) = o;
}

// ---------------- Weight transpose + cast: W[k][j] fp32 -> WT[j][k] fp16 ----
__global__ __launch_bounds__(256) void wtrans_kernel(const float* __restrict__ Wq, const float* __restrict__ Wk,
                                                     const float* __restrict__ Wv, const float* __restrict__ Wo,
                                                     _Float16* __restrict__ Tq, _Float16* __restrict__ Tk,
                                                     _Float16* __restrict__ Tv, _Float16* __restrict__ To) {
    __shared__ float tile[32][33];
    int m = blockIdx.z;
    const float* W = (m == 0) ? Wq : (m == 1) ? Wk : (m == 2) ? Wv : Wo;
    _Float16*    T = (m == 0) ? Tq : (m == 1) ? Tk : (m == 2) ? Tv : To;
    int j0 = blockIdx.x * 32, k0 = blockIdx.y * 32;
    int tx = threadIdx.x, ty = threadIdx.y;   // 32 x 8
    #pragma unroll
    for (int i = 0; i < 4; i++) tile[ty + i*8][tx] = W[(size_t)(k0 + ty + i*8) * DIM + j0 + tx];
    __syncthreads();
    #pragma unroll
    for (int i = 0; i < 4; i++) T[(size_t)(j0 + ty + i*8) * DIM + k0 + tx] = (_Float16)tile[tx][ty + i*8];
}

// ---------------- GEMM: C = A @ BT^T, A[M][1024] f16, BT[1024][1024] f16 ----
template<int MODE>
__global__ __launch_bounds__(256) void gemm_bt(const _Float16* __restrict__ A,
                                               const _Float16* __restrict__ BT,
                                               void* __restrict__ Cout,
                                               const float* __restrict__ bias) {
    __shared__ _Float16 As[128 * 32];
    __shared__ _Float16 Bs[128 * 32];
    const int K = DIM;
    int m0 = blockIdx.x * 128, n0 = blockIdx.y * 128;
    int t = threadIdx.x, w = t >> 6, l = t & 63;
    int wr = w >> 1, wc = w & 1, ln = l & 15, qtr = l >> 4;
    f32x4 acc[4][4] = {};
    int srow = t >> 2, scol = (t & 3) * 8;
    const _Float16* Ag = A  + (size_t)(m0 + srow) * K + scol;
    const _Float16* Bg = BT + (size_t)(n0 + srow) * K + scol;
    _Float16* Al = &As[(w * 16) * 32];   // wave-uniform LDS base
    _Float16* Bl = &Bs[(w * 16) * 32];
    for (int kt = 0; kt < K; kt += 32) {
        gload16(Ag,                    Al);
        gload16(Ag + (size_t)64 * K,   Al + 64 * 32);
        gload16(Bg,                    Bl);
        gload16(Bg + (size_t)64 * K,   Bl + 64 * 32);
        Ag += 32; Bg += 32;
        __syncthreads();
        f16x8 af[4], bfr[4];
        #pragma unroll
        for (int r = 0; r < 4; r++) af[r]  = *(const f16x8*)&As[(wr * 64 + r * 16 + ln) * 32 + qtr * 8];
        #pragma unroll
        for (int c = 0; c < 4; c++) bfr[c] = *(const f16x8*)&Bs[(wc * 64 + c * 16 + ln) * 32 + qtr * 8];
        #pragma unroll
        for (int r = 0; r < 4; r++)
            #pragma unroll
            for (int c = 0; c < 4; c++)
                acc[r][c] = __builtin_amdgcn_mfma_f32_16x16x32_f16(af[r], bfr[c], acc[r][c], 0, 0, 0);
        __syncthreads();
    }
    #pragma unroll
    for (int r = 0; r < 4; r++)
        #pragma unroll
        for (int c = 0; c < 4; c++) {
            int gn = n0 + wc * 64 + c * 16 + ln;
            #pragma unroll
            for (int q = 0; q < 4; q++) {
                int gm = m0 + wr * 64 + r * 16 + qtr * 4 + q;
                float v = acc[r][c][q];
                if constexpr (MODE == 0) {
                    int b = gm >> 10, n = gm & 1023, h = gn >> 6, d = gn & 63;
                    ((_Float16*)Cout)[(((size_t)(b * HEADS + h) * NTOK + n) << 6) + d] = (_Float16)v;
                } else if constexpr (MODE == 2) {
                    int b = gm >> 10, n = gm & 1023, h = gn >> 6, d = gn & 63;
                    ((_Float16*)Cout)[(((size_t)(b * HEADS + h) * HD + d) << 10) + n] = (_Float16)v;
                } else {
                    ((float*)Cout)[(size_t)gm * DIM + gn] = v + bias[gn];
                }
            }
        }
}

// ---------------- Fused flash attention -----------------------------------
// Block = (b, h, 128 q rows); 4 waves x 32 q rows each (qf=0,1 -> 16-row tiles).
// Swapped QK^T: st = mfma(Kfrag, Qfrag) -> lane ln owns q-row (qf*16+ln).
// K/V 64x64 f16 tiles double-buffered in LDS via global_load_lds with
// pre-swizzled source chunks (chunk ^= row&7) -> conflict-free ds_read_b128.
__global__ __launch_bounds__(256) void attn_kernel(const _Float16* __restrict__ qb,
                                                   const _Float16* __restrict__ kb,
                                                   const _Float16* __restrict__ vt,
                                                   const float* __restrict__ bias,
                                                   _Float16* __restrict__ ao) {
    __shared__ _Float16 Kt[2][64 * 64];
    __shared__ _Float16 Vs[2][64 * 64];
    int bid = blockIdx.x;
    int id2 = (bid & 7) * 128 + (bid >> 3);          // XCD swizzle (1024 % 8 == 0)
    int qt = id2 & 7, h = (id2 >> 3) & 15, b = id2 >> 7;
    int q0 = qt * 128;
    int t = threadIdx.x, w = t >> 6, l = t & 63, ln = l & 15, qtr = l >> 4;
    const _Float16* qbase = qb + (size_t)(b * HEADS + h) * NTOK * HD;
    const _Float16* kbase = kb + (size_t)(b * HEADS + h) * NTOK * HD;
    const _Float16* vbase = vt + (size_t)(b * HEADS + h) * HD * NTOK;
    const float*    bbase = bias + ((size_t)h * NTOK + q0 + w * 32) * NTOK;

    // Q fragments (B-operand): lane ln = q col, qtr*8 = k offset
    f16x8 qfr[2][2];
    #pragma unroll
    for (int qf = 0; qf < 2; qf++)
        #pragma unroll
        for (int ks = 0; ks < 2; ks++)
            qfr[qf][ks] = *(const f16x8*)&qbase[(size_t)(q0 + w*32 + qf*16 + ln) * HD + ks*32 + qtr*8];

#define STAGE(BUF, J0) do {                                                     \
        int rb_ = w * 16;                                                       \
        _Float16* kl_ = &Kt[BUF][rb_ * 64];                                     \
        _Float16* vl_ = &Vs[BUF][rb_ * 64];                                     \
        int r_ = rb_ + (l >> 3); int cg_ = (l & 7) ^ (r_ & 7);                  \
        gload16(kbase + (size_t)((J0) + r_) * HD + cg_ * 8, kl_);               \
        gload16(vbase + (size_t)r_ * NTOK + (J0) + cg_ * 8, vl_);               \
        r_ += 8; cg_ = (l & 7) ^ (r_ & 7);                                      \
        gload16(kbase + (size_t)((J0) + r_) * HD + cg_ * 8, kl_ + 8 * 64);      \
        gload16(vbase + (size_t)r_ * NTOK + (J0) + cg_ * 8, vl_ + 8 * 64);      \
    } while (0)

    STAGE(0, 0);
    __syncthreads();

    float m_run[2] = {-3.0e38f, -3.0e38f};
    float l_run[2] = {0.f, 0.f};
    f32x4 acc[2][4] = {};

    for (int tt = 0; tt < 16; tt++) {
        int cur = tt & 1;
        if (tt < 15) STAGE(cur ^ 1, (tt + 1) * 64);

        // ---- QK^T (swapped): st2[qf][r][m] = S[j=tt*64+r*16+qtr*4+m][q=qf*16+ln]
        f32x4 st2[2][4] = {};
        #pragma unroll
        for (int r = 0; r < 4; r++) {
            int row = r * 16 + ln;
            #pragma unroll
            for (int ks = 0; ks < 2; ks++) {
                f16x8 kf = *(const f16x8*)&Kt[cur][row * 64 + (((qtr + ks*4) ^ (ln & 7)) * 8)];
                st2[0][r] = __builtin_amdgcn_mfma_f32_16x16x32_f16(kf, qfr[0][ks], st2[0][r], 0, 0, 0);
                st2[1][r] = __builtin_amdgcn_mfma_f32_16x16x32_f16(kf, qfr[1][ks], st2[1][r], 0, 0, 0);
            }
        }

        // ---- online softmax + P-fragment build, per qf
        f16x8 pfr[2][2];
        #pragma unroll
        for (int qf = 0; qf < 2; qf++) {
            const float* bq = bbase + (size_t)(qf*16 + ln) * NTOK + tt*64 + qtr*4;
            float sv[4][4];
            float pmax = -3.0e38f;
            #pragma unroll
            for (int r = 0; r < 4; r++) {
                float4 bb = *(const float4*)(bq + r * 16);
                float s0 = st2[qf][r][0] * 0.125f + bb.x;
                float s1 = st2[qf][r][1] * 0.125f + bb.y;
                float s2 = st2[qf][r][2] * 0.125f + bb.z;
                float s3 = st2[qf][r][3] * 0.125f + bb.w;
                sv[r][0] = s0; sv[r][1] = s1; sv[r][2] = s2; sv[r][3] = s3;
                pmax = fmaxf(pmax, fmaxf(fmaxf(s0, s1), fmaxf(s2, s3)));
            }
            pmax = fmaxf(pmax, __shfl_xor(pmax, 16, 64));
            pmax = fmaxf(pmax, __shfl_xor(pmax, 32, 64));
            if (__any(pmax > m_run[qf])) {            // wave-uniform rescale
                float mnew = fmaxf(m_run[qf], pmax);
                float f = __expf(m_run[qf] - mnew);
                m_run[qf] = mnew;
                l_run[qf] *= f;
                float fm[4];
                #pragma unroll
                for (int m = 0; m < 4; m++) fm[m] = __shfl(f, (l & 48) | (qtr * 4 + m), 64);
                #pragma unroll
                for (int dg = 0; dg < 4; dg++)
                    #pragma unroll
                    for (int m = 0; m < 4; m++) acc[qf][dg][m] *= fm[m];
            }
            float sig = 0.f;
            unsigned pk2[4][2];
            #pragma unroll
            for (int r = 0; r < 4; r++) {
                float p0 = __expf(sv[r][0] - m_run[qf]);
                float p1 = __expf(sv[r][1] - m_run[qf]);
                float p2 = __expf(sv[r][2] - m_run[qf]);
                float p3 = __expf(sv[r][3] - m_run[qf]);
                sig += (p0 + p1) + (p2 + p3);
                pk2[r][0] = pkrtz(p0, p1);
                pk2[r][1] = pkrtz(p2, p3);
            }
            sig += __shfl_xor(sig, 16, 64);
            sig += __shfl_xor(sig, 32, 64);
            l_run[qf] += sig;

            // in-register P^T -> A-frag exchange (verified lane algebra)
            #pragma unroll
            for (int ks = 0; ks < 2; ks++) {
                unsigned pw[4];
                #pragma unroll
                for (int c = 0; c < 2; c++) {
                    unsigned X = pk2[2*ks][c], Y = pk2[2*ks + 1][c];
                    unsigned Z  = (qtr < 2) ? X : Y;
                    unsigned Wv = (qtr < 2) ? Y : X;
                    unsigned Vv = (unsigned)__shfl_xor((int)Wv, 32, 64);
                    unsigned U  = (qtr & 2) ? Vv : Z;
                    unsigned T  = (qtr & 2) ? Z : Vv;
                    unsigned sU = (unsigned)__shfl_xor((int)U, 16, 64);
                    unsigned sT = (unsigned)__shfl_xor((int)T, 16, 64);
                    pw[c]     = (qtr & 1) ? sT : U;   // elems e=0..3  (quad c0,c1)
                    pw[2 + c] = (qtr & 1) ? T : sU;   // elems e=4..7
                }
                pfr[qf][ks] = __builtin_bit_cast(f16x8, *(const uint4*)pw);
            }
        }

        // ---- PV: acc[qf][dg] += P @ V
        #pragma unroll
        for (int dg = 0; dg < 4; dg++) {
            int row = dg * 16 + ln;
            #pragma unroll
            for (int ks = 0; ks < 2; ks++) {
                f16x8 vf = *(const f16x8*)&Vs[cur][row * 64 + (((qtr + ks*4) ^ (ln & 7)) * 8)];
                acc[0][dg] = __builtin_amdgcn_mfma_f32_16x16x32_f16(pfr[0][ks], vf, acc[0][dg], 0, 0, 0);
                acc[1][dg] = __builtin_amdgcn_mfma_f32_16x16x32_f16(pfr[1][ks], vf, acc[1][dg], 0, 0, 0);
            }
        }
        __syncthreads();
    }

    // ---- epilogue: divide by row-sum, store f16
    #pragma unroll
    for (int qf = 0; qf < 2; qf++) {
        float inv = 1.0f / l_run[qf];
        float invm[4];
        #pragma unroll
        for (int m = 0; m < 4; m++) invm[m] = __shfl(inv, (l & 48) | (qtr * 4 + m), 64);
        size_t rowb = (size_t)b * NTOK + q0 + w * 32 + qf * 16 + qtr * 4;
        #pragma unroll
        for (int dg = 0; dg < 4; dg++)
            #pragma unroll
            for (int m = 0; m < 4; m++)
                ao[(rowb + m) * DIM + h * HD + dg * 16 + ln] = (_Float16)(acc[qf][dg][m] * invm[m]);
    }
#undef STAGE
}

extern "C" void kernel_launch(void* const* d_in, const int* in_sizes, int n_in,
                              void* d_out, int out_size, void* d_ws, size_t ws_size,
                              hipStream_t stream) {
    const float* x     = (const float*)d_in[0];
    const float* ctx   = (const float*)d_in[1];
    const float* bias  = (const float*)d_in[2];
    const float* Wq    = (const float*)d_in[3];
    const float* Wk    = (const float*)d_in[4];
    const float* Wv    = (const float*)d_in[5];
    const float* Wo    = (const float*)d_in[6];
    const float* bo    = (const float*)d_in[7];
    const float* gamma = (const float*)d_in[8];
    const float* beta  = (const float*)d_in[9];
    float* out = (float*)d_out;

    _Float16* ws  = (_Float16*)d_ws;
    _Float16* xn  = ws;                                  // 8192*1024
    _Float16* cn  = xn  + (size_t)MROWS * DIM;           // 8192*1024
    _Float16* wqT = cn  + (size_t)MROWS * DIM;           // 1024*1024
    _Float16* wkT = wqT + (size_t)DIM * DIM;
    _Float16* wvT = wkT + (size_t)DIM * DIM;
    _Float16* woT = wvT + (size_t)DIM * DIM;
    _Float16* qbf = woT + (size_t)DIM * DIM;             // [b][h][n][d]
    _Float16* kbf = qbf + (size_t)MROWS * DIM;           // [b][h][n][d]
    _Float16* vtb = kbf + (size_t)MROWS * DIM;           // [b][h][d][n]
    _Float16* aob = vtb + (size_t)MROWS * DIM;           // [b][n][h*d]

    ln_kernel<<<dim3(2 * MROWS), dim3(256), 0, stream>>>(x, ctx, gamma, beta, xn, cn);
    wtrans_kernel<<<dim3(32, 32, 4), dim3(32, 8), 0, stream>>>(Wq, Wk, Wv, Wo, wqT, wkT, wvT, woT);
    gemm_bt<0><<<dim3(64, 8), dim3(256), 0, stream>>>(xn, wqT, qbf, nullptr);
    gemm_bt<0><<<dim3(64, 8), dim3(256), 0, stream>>>(cn, wkT, kbf, nullptr);
    gemm_bt<2><<<dim3(64, 8), dim3(256), 0, stream>>>(cn, wvT, vtb, nullptr);
    attn_kernel<<<dim3(NB * HEADS * 8), dim3(256), 0, stream>>>(qbf, kbf, vtb, bias, aob);
    gemm_bt<3><<<dim3(64, 8), dim3(256), 0, stream>>>(aob, woT, out, bo);
}